// Round 1
// 184.387 us; speedup vs baseline: 1.1002x; 1.1002x over previous
//
#include <hip/hip_runtime.h>
#include <hip/hip_bf16.h>
#include <stdint.h>

// LinearTimeSelfAttention MI355X, round 5:
//  - k2a eliminated: k1 atomically accumulates ctx partials into 8 replicas
//    (ctxP[8][4224], L2-resident, zeroed by hipMemsetAsync) -> saves the k2a
//    dispatch + 17.3 MB of cpart HBM round-trip.
//  - k2bc widened to 256 threads (read phase 2x).
//  - k1 per-head wave mapping, depth-2 register prefetch; k3 unchanged.
// Folding: y = Bm@x + cvec; Bm = A@W_q; A = (W_out ctx)/S;
// ctx = sum_n e^k v^T; S = sum_n e^k.

#define NPOS 147456      // 384*384
#define NTILES 2304      // NPOS / 64
#define NB1 512          // 2 blocks/CU exactly

typedef __attribute__((ext_vector_type(8))) short short8;
typedef __attribute__((ext_vector_type(4))) float floatx4;

__device__ __forceinline__ uint16_t f2bf(float f) {
    uint32_t u = __float_as_uint(f);
    return (uint16_t)((u + 0x7fffu + ((u >> 16) & 1u)) >> 16);   // RNE
}
__device__ __forceinline__ uint32_t pack2(float a, float b) {
#if __has_builtin(__builtin_amdgcn_cvt_pk_bf16_f32)
    auto r = __builtin_amdgcn_cvt_pk_bf16_f32(a, b);
    uint32_t u; __builtin_memcpy(&u, &r, sizeof(u));
    return u;
#else
    return (uint32_t)f2bf(a) | ((uint32_t)f2bf(b) << 16);
#endif
}

// strides in 32-bit LDS words
#define XS_STRIDE 68     // 136 bf16 per n-row (128 ch + 8 pad)
#define PS_STRIDE 36     // 72 bf16 per kvrow (64 n + 8 pad)

// ---- k1 helpers ----
__device__ __forceinline__ void k1_load(const float* __restrict__ xb, float* pf) {
    #pragma unroll
    for (int i = 0; i < 32; ++i) pf[i] = xb[(size_t)i * NPOS];
}
__device__ __forceinline__ void k1_store(uint32_t* Xsbuf, const float* pf, int lane, int c0) {
    #pragma unroll
    for (int i = 0; i < 8; ++i) {
        uint2 w;
        w.x = pack2(pf[i * 4 + 0], pf[i * 4 + 1]);
        w.y = pack2(pf[i * 4 + 2], pf[i * 4 + 3]);
        *(uint2*)&Xsbuf[lane * XS_STRIDE + (c0 + i * 4) / 2] = w;
    }
}
__device__ __forceinline__ void k1_tile(
    const uint32_t* __restrict__ Xsbuf, uint32_t* __restrict__ Psw,
    const short8 (&wfr)[4][4], const float (&biasv)[4],
    floatx4 (&acc2)[4], float (&sacc)[2], int m, int quad)
{
    // phase A: P^T[n][local kvrow] = X^T W^T + b   (local rows: 0-31 k, 32-63 v)
    #pragma unroll
    for (int nt = 0; nt < 4; ++nt) {
        short8 afr[4];
        #pragma unroll
        for (int ks = 0; ks < 4; ++ks)
            afr[ks] = *(const short8*)&Xsbuf[(nt * 16 + m) * XS_STRIDE + ks * 16 + quad * 4];
        floatx4 pa[4];
        #pragma unroll
        for (int kt = 0; kt < 4; ++kt) pa[kt] = (floatx4){0.f, 0.f, 0.f, 0.f};
        #pragma unroll
        for (int ks = 0; ks < 4; ++ks)
            #pragma unroll
            for (int kt = 0; kt < 4; ++kt)
                pa[kt] = __builtin_amdgcn_mfma_f32_16x16x32_bf16(afr[ks], wfr[kt][ks], pa[kt], 0, 0, 0);
        #pragma unroll
        for (int kt = 0; kt < 4; ++kt) {
            float v0 = pa[kt][0] + biasv[kt];
            float v1 = pa[kt][1] + biasv[kt];
            float v2 = pa[kt][2] + biasv[kt];
            float v3 = pa[kt][3] + biasv[kt];
            if (kt < 2) {   // k rows of this head
                v0 = __expf(v0); v1 = __expf(v1);
                v2 = __expf(v2); v3 = __expf(v3);
                sacc[kt] += (v0 + v1) + (v2 + v3);
            }
            uint2 w;
            w.x = pack2(v0, v1);
            w.y = pack2(v2, v3);
            *(uint2*)&Psw[(kt * 16 + m) * PS_STRIDE + nt * 8 + quad * 2] = w;
        }
    }
    // phase B: ctx += Ek V^T — reads ONLY this wave's Ps region (no barrier)
    #pragma unroll
    for (int ks = 0; ks < 2; ++ks) {
        short8 ea[2], vb[2];
        #pragma unroll
        for (int dt = 0; dt < 2; ++dt)
            ea[dt] = *(const short8*)&Psw[(dt * 16 + m) * PS_STRIDE + ks * 16 + quad * 4];
        #pragma unroll
        for (int et = 0; et < 2; ++et)
            vb[et] = *(const short8*)&Psw[(32 + et * 16 + m) * PS_STRIDE + ks * 16 + quad * 4];
        #pragma unroll
        for (int dt = 0; dt < 2; ++dt)
            #pragma unroll
            for (int et = 0; et < 2; ++et)
                acc2[dt * 2 + et] = __builtin_amdgcn_mfma_f32_16x16x32_bf16(ea[dt], vb[et], acc2[dt * 2 + et], 0, 0, 0);
    }
}

// ---------------- K1: projections + exp + partial context (atomic reduce) ----------------
__global__ __launch_bounds__(256, 2) void k1_ctx(
    const float* __restrict__ x, const float* __restrict__ w_qkv,
    const float* __restrict__ b_qkv, float* __restrict__ ctxP, int nb1)
{
    __shared__ uint32_t Xs[2][64 * XS_STRIDE];
    __shared__ uint32_t Ps[256 * PS_STRIDE];     // 4 wave-private 64-row regions

    const int t = threadIdx.x;
    const int lane = t & 63;
    const int wavu = __builtin_amdgcn_readfirstlane(t >> 6);
    const int m = lane & 15, quad = lane >> 4;
    const int c0 = wavu * 32;
    uint32_t* const Psw = &Ps[wavu * 64 * PS_STRIDE];

    // W fragments: wave h holds k-rows h*32..+31 (kt 0,1) and v-rows h*32..+31 (kt 2,3)
    short8 wfr[4][4];
    float biasv[4];
    #pragma unroll
    for (int kt = 0; kt < 4; ++kt) {
        const int row = (kt < 2 ? 128 + wavu * 32 + kt * 16
                                : 256 + wavu * 32 + (kt - 2) * 16) + m;
        biasv[kt] = b_qkv[row];
        #pragma unroll
        for (int ks = 0; ks < 4; ++ks) {
            const float* p = w_qkv + row * 128 + ks * 32 + quad * 8;
            short8 w;
            #pragma unroll
            for (int j = 0; j < 8; ++j) w[j] = (short)f2bf(p[j]);
            wfr[kt][ks] = w;
        }
    }

    floatx4 acc2[4];
    #pragma unroll
    for (int i = 0; i < 4; ++i) acc2[i] = (floatx4){0.f, 0.f, 0.f, 0.f};
    float sacc[2] = {0.f, 0.f};

    const float* xw = x + (size_t)c0 * NPOS + lane;   // wave's channel slab base
    float pfA[32], pfB[32];

    // prologue: load tiles b, b+nb1; stage b into Xs[0]
    k1_load(xw + blockIdx.x * 64, pfA);
    if (blockIdx.x + nb1 < NTILES) k1_load(xw + (blockIdx.x + nb1) * 64, pfB);
    k1_store(Xs[0], pfA, lane, c0);
    __syncthreads();

    for (int tile = blockIdx.x; tile < NTILES; tile += 2 * nb1) {
        const int t1 = tile + nb1, t2 = tile + 2 * nb1, t3 = tile + 3 * nb1;
        // --- half 1: consume Xs[0] (tile), prefetch t2 -> pfA, stage pfB(t1) -> Xs[1]
        if (t2 < NTILES) k1_load(xw + t2 * 64, pfA);
        k1_tile(Xs[0], Psw, wfr, biasv, acc2, sacc, m, quad);
        if (t1 < NTILES) k1_store(Xs[1], pfB, lane, c0);
        __syncthreads();
        // --- half 2: consume Xs[1] (t1), prefetch t3 -> pfB, stage pfA(t2) -> Xs[0]
        if (t1 < NTILES) {
            if (t3 < NTILES) k1_load(xw + t3 * 64, pfB);
            k1_tile(Xs[1], Psw, wfr, biasv, acc2, sacc, m, quad);
            if (t2 < NTILES) k1_store(Xs[0], pfA, lane, c0);
            __syncthreads();
        }
    }

    // atomic partial reduce into replica (blockIdx & 7):
    // [0..4095] ctx (h*1024 + d*32 + e), [4096..4223] S
    float* __restrict__ dst = ctxP + (size_t)(blockIdx.x & 7) * 4224;
    #pragma unroll
    for (int dt = 0; dt < 2; ++dt)
        #pragma unroll
        for (int et = 0; et < 2; ++et)
            #pragma unroll
            for (int r = 0; r < 4; ++r) {
                const int d = dt * 16 + quad * 4 + r, e = et * 16 + m;
                atomicAdd(&dst[wavu * 1024 + d * 32 + e], acc2[dt * 2 + et][r]);
            }
    #pragma unroll
    for (int kt = 0; kt < 2; ++kt) {
        float s = sacc[kt];
        s += __shfl_down(s, 32, 64);
        s += __shfl_down(s, 16, 64);
        if (lane < 16) atomicAdd(&dst[4096 + wavu * 32 + kt * 16 + lane], s);
    }
}

// ---------------- K2bc: per-o A row -> bf16 Bm row + cvec ----------------
__global__ __launch_bounds__(256) void k2bc(
    const float* __restrict__ ctxP, const float* __restrict__ w_out,
    const float* __restrict__ w_qkv, const float* __restrict__ b_qkv,
    const float* __restrict__ b_out, uint32_t* __restrict__ Bmb, float* __restrict__ cvec)
{
    __shared__ float ctx33[128 * 33];
    __shared__ float Ss[128];
    __shared__ float Arow[128];
    __shared__ float row[128];
    __shared__ float red[128];
    const int o = blockIdx.x, t = threadIdx.x;
    for (int j = t; j < 4224; j += 256) {
        float s = 0.f;
        #pragma unroll
        for (int p = 0; p < 8; ++p) s += ctxP[p * 4224 + j];
        if (j < 4096) ctx33[(j >> 5) * 33 + (j & 31)] = s;
        else          Ss[j - 4096] = s;
    }
    __syncthreads();
    if (t < 128) {   // A[o][hd], hd = t
        const int h = t >> 5;
        float s = 0.f;
        #pragma unroll
        for (int e = 0; e < 32; ++e)
            s = fmaf(w_out[o * 128 + h * 32 + e], ctx33[t * 33 + e], s);
        Arow[t] = s / Ss[t];
    }
    __syncthreads();
    if (t < 128) {   // Bm[o][c], c = t
        float s = 0.f;
        #pragma unroll 16
        for (int hd = 0; hd < 128; ++hd)
            s = fmaf(Arow[hd], w_qkv[hd * 128 + t], s);
        row[t] = s;
        red[t] = Arow[t] * b_qkv[t];
    }
    __syncthreads();
    if (t < 64) Bmb[o * 64 + t] = pack2(row[2 * t], row[2 * t + 1]);
    if (t == 0) {
        float cs = b_out[o];
        #pragma unroll 8
        for (int i = 0; i < 128; ++i) cs += red[i];
        cvec[o] = cs;
    }
}

// ---------------- K3: y = Bm @ x + cvec ----------------
__global__ __launch_bounds__(256) void k3(
    const float* __restrict__ x, const uint32_t* __restrict__ Bmb,
    const float* __restrict__ cvec, float* __restrict__ y)
{
    __shared__ uint32_t Xs[64 * XS_STRIDE];
    const int t = threadIdx.x, lane = t & 63;
    const int wavu = __builtin_amdgcn_readfirstlane(t >> 6);
    const int m = lane & 15, quad = lane >> 4;
    const int n0 = blockIdx.x * 64;
    const int c0 = wavu * 32;

    // stage X^T first (get loads in flight)
    float pf[32];
    k1_load(x + (size_t)c0 * NPOS + n0 + lane, pf);

    // Bm fragments from packed bf16 rows: 8 x dwordx4
    short8 bfr[2][4];
    float cv[2];
    #pragma unroll
    for (int ot = 0; ot < 2; ++ot) {
        const int o = (wavu * 2 + ot) * 16 + m;
        cv[ot] = cvec[o];
        #pragma unroll
        for (int ks = 0; ks < 4; ++ks)
            bfr[ot][ks] = *(const short8*)&Bmb[o * 64 + ks * 16 + quad * 4];
    }
    k1_store(Xs, pf, lane, c0);
    __syncthreads();

    floatx4 acc[2][4];
    #pragma unroll
    for (int ot = 0; ot < 2; ++ot)
        #pragma unroll
        for (int nt = 0; nt < 4; ++nt) acc[ot][nt] = (floatx4){0.f, 0.f, 0.f, 0.f};
    #pragma unroll
    for (int nt = 0; nt < 4; ++nt) {
        short8 afr[4];
        #pragma unroll
        for (int ks = 0; ks < 4; ++ks)
            afr[ks] = *(const short8*)&Xs[(nt * 16 + m) * XS_STRIDE + ks * 16 + quad * 4];
        #pragma unroll
        for (int ks = 0; ks < 4; ++ks)
            #pragma unroll
            for (int ot = 0; ot < 2; ++ot)
                acc[ot][nt] = __builtin_amdgcn_mfma_f32_16x16x32_bf16(afr[ks], bfr[ot][ks], acc[ot][nt], 0, 0, 0);
    }
    #pragma unroll
    for (int ot = 0; ot < 2; ++ot) {
        const int o = (wavu * 2 + ot) * 16 + m;
        #pragma unroll
        for (int nt = 0; nt < 4; ++nt) {
            floatx4 v = acc[ot][nt];
            v.x += cv[ot]; v.y += cv[ot]; v.z += cv[ot]; v.w += cv[ot];
            *(floatx4*)(y + (size_t)o * NPOS + n0 + nt * 16 + quad * 4) = v;
        }
    }
}

extern "C" void kernel_launch(void* const* d_in, const int* in_sizes, int n_in,
                              void* d_out, int out_size, void* d_ws, size_t ws_size,
                              hipStream_t stream)
{
    const float* x     = (const float*)d_in[0];
    const float* w_qkv = (const float*)d_in[1];
    const float* b_qkv = (const float*)d_in[2];
    const float* w_out = (const float*)d_in[3];
    const float* b_out = (const float*)d_in[4];
    float* y = (float*)d_out;

    // ws: ctxP[8][4224] | Bmb[8192 u32] | cvec[128]   (~168 KB total)
    char* wsb = (char*)d_ws;
    float* ctxP    = (float*)wsb;
    uint32_t* Bmb  = (uint32_t*)(wsb + (size_t)8 * 4224 * 4);
    float* cvec    = (float*)(wsb + (size_t)8 * 4224 * 4 + (size_t)8192 * 4);

    hipMemsetAsync(ctxP, 0, (size_t)8 * 4224 * sizeof(float), stream);
    hipLaunchKernelGGL(k1_ctx, dim3(NB1), dim3(256), 0, stream, x, w_qkv, b_qkv, ctxP, NB1);
    hipLaunchKernelGGL(k2bc, dim3(128), dim3(256), 0, stream, ctxP, w_out, w_qkv, b_qkv, b_out, Bmb, cvec);
    hipLaunchKernelGGL(k3, dim3(NTILES), dim3(256), 0, stream, x, Bmb, cvec, y);
}